// Round 2
// baseline (191.960 us; speedup 1.0000x reference)
//
#include <hip/hip_runtime.h>
#include <hip/hip_bf16.h>

typedef short bf16x8 __attribute__((ext_vector_type(8)));
typedef float f32x4 __attribute__((ext_vector_type(4)));

#define T_DIM 2048
#define D_DIM 64
#define WIN 128
#define QBLK 64
#define KWMAX 320
#define NKT_MAX 20
#define NS_MAX 10
#define NEGBIG -1e30f

__device__ __forceinline__ short f2b(float x) {
  __hip_bfloat16 h = __float2bfloat16(x);
  return *reinterpret_cast<short*>(&h);
}
__device__ __forceinline__ bf16x8 cvt8(f32x4 a, f32x4 b) {
  bf16x8 r;
  r[0] = f2b(a[0]); r[1] = f2b(a[1]); r[2] = f2b(a[2]); r[3] = f2b(a[3]);
  r[4] = f2b(b[0]); r[5] = f2b(b[1]); r[6] = f2b(b[2]); r[7] = f2b(b[3]);
  return r;
}
// swizzled byte address inside a row-major LDS tile, 640B rows (Vt, P)
__device__ __forceinline__ int swzP(int row, int b) { return row * 640 + (b ^ ((row & 7) << 4)); }

__global__ __launch_bounds__(256, 2) void lsa_fused(
    const float* __restrict__ Qg, const float* __restrict__ Kg,
    const float* __restrict__ Vg, float* __restrict__ Og,
    float* __restrict__ Ag) {
  const int tid = threadIdx.x;
  const int role = blockIdx.x & 1;          // 1 = zero-fill block, 0 = attention block
  const int q0 = (blockIdx.x >> 1) * QBLK;
  const int bh = blockIdx.y;
  int kstart = q0 - WIN; if (kstart < 0) kstart = 0;
  int kend = q0 + QBLK + WIN; if (kend > T_DIM) kend = T_DIM;

  float* aptr = Ag + (size_t)bh * ((size_t)T_DIM * T_DIM);

  if (role) {
    // ---- pure streaming zero-fill of out-of-band attn columns ----
    const f32x4 z = {0.f, 0.f, 0.f, 0.f};
    float* arow = aptr + (size_t)q0 * T_DIM;
    for (int r = 0; r < QBLK; ++r, arow += T_DIM) {
      for (int c = tid * 4; c < kstart; c += 1024) *(f32x4*)(arow + c) = z;
      for (int c = kend + tid * 4; c < T_DIM; c += 1024) *(f32x4*)(arow + c) = z;
    }
    return;
  }

  const int KW = kend - kstart;   // 192 / 256 / 320, always multiple of 32
  const int nkt = KW >> 4;        // 16-wide k tiles
  const int ns = KW >> 5;         // 32-wide k slices

  const float* qptr = Qg + (size_t)bh * (T_DIM * D_DIM);
  const float* kptr = Kg + (size_t)bh * (T_DIM * D_DIM);
  const float* vptr = Vg + (size_t)bh * (T_DIM * D_DIM);
  float* optr = Og + (size_t)bh * (T_DIM * D_DIM);

  // LDS: Vt 40KB + P 40KB = 80KB -> 2 blocks/CU
  __shared__ __align__(16) char Vb[D_DIM * 640];
  __shared__ __align__(16) char Pb[QBLK * 640];

  // ---- stage V transposed: Vt[d][k] bf16, 640B rows, swizzled ----
  for (int idx = tid; idx < KW * 16; idx += 256) {
    const int r = idx >> 4, c4 = idx & 15;
    f32x4 f = *(const f32x4*)(vptr + (size_t)(kstart + r) * D_DIM + c4 * 4);
    const int d0 = c4 * 4;
    *(short*)(Vb + swzP(d0 + 0, r * 2)) = f2b(f[0]);
    *(short*)(Vb + swzP(d0 + 1, r * 2)) = f2b(f[1]);
    *(short*)(Vb + swzP(d0 + 2, r * 2)) = f2b(f[2]);
    *(short*)(Vb + swzP(d0 + 3, r * 2)) = f2b(f[3]);
  }
  __syncthreads();

  const int lane = tid & 63;
  const int w = tid >> 6;       // wave id -> q sub-tile
  const int c = lane & 15;      // col within 16x16 tile
  const int hi = lane >> 4;     // 0..3

  // ---- Q A-frags direct from global (fp32 -> bf16) ----
  const float* qrow = qptr + (size_t)(q0 + w * 16 + c) * D_DIM + 8 * hi;
  bf16x8 a0 = cvt8(*(const f32x4*)(qrow),      *(const f32x4*)(qrow + 4));
  bf16x8 a1 = cvt8(*(const f32x4*)(qrow + 32), *(const f32x4*)(qrow + 36));

  // ---- S = Q K^T over the window (K frags direct from global) ----
  f32x4 acc[NKT_MAX];
#pragma unroll
  for (int kt = 0; kt < NKT_MAX; ++kt) {
    acc[kt] = (f32x4){0.f, 0.f, 0.f, 0.f};
    if (kt < nkt) {
      const float* krow = kptr + (size_t)(kstart + kt * 16 + c) * D_DIM + 8 * hi;
      bf16x8 b0 = cvt8(*(const f32x4*)(krow),      *(const f32x4*)(krow + 4));
      bf16x8 b1 = cvt8(*(const f32x4*)(krow + 32), *(const f32x4*)(krow + 36));
      acc[kt] = __builtin_amdgcn_mfma_f32_16x16x32_bf16(a0, b0, acc[kt], 0, 0, 0);
      acc[kt] = __builtin_amdgcn_mfma_f32_16x16x32_bf16(a1, b1, acc[kt], 0, 0, 0);
    }
  }

  // ---- masked softmax (fp32), write attn band + P bf16 to LDS ----
  const int kgc = kstart + c;
#pragma unroll
  for (int j = 0; j < 4; ++j) {
    const int qrow_i = q0 + w * 16 + 4 * hi + j;
    float m = NEGBIG;
#pragma unroll
    for (int kt = 0; kt < NKT_MAX; ++kt)
      if (kt < nkt) {
        const int kcol = kgc + kt * 16;
        float s = acc[kt][j] * 0.125f;           // 1/sqrt(64)
        int dist = qrow_i - kcol; dist = dist < 0 ? -dist : dist;
        s = (dist <= WIN) ? s : NEGBIG;
        acc[kt][j] = s;
        m = fmaxf(m, s);
      }
    m = fmaxf(m, __shfl_xor(m, 1));
    m = fmaxf(m, __shfl_xor(m, 2));
    m = fmaxf(m, __shfl_xor(m, 4));
    m = fmaxf(m, __shfl_xor(m, 8));
    float sum = 0.f;
#pragma unroll
    for (int kt = 0; kt < NKT_MAX; ++kt)
      if (kt < nkt) {
        float p = __expf(acc[kt][j] - m);
        acc[kt][j] = p;
        sum += p;
      }
    sum += __shfl_xor(sum, 1);
    sum += __shfl_xor(sum, 2);
    sum += __shfl_xor(sum, 4);
    sum += __shfl_xor(sum, 8);
    const float inv = 1.f / sum;
    float* arow = aptr + (size_t)qrow_i * T_DIM;
#pragma unroll
    for (int kt = 0; kt < NKT_MAX; ++kt)
      if (kt < nkt) {
        float p = acc[kt][j] * inv;
        arow[kgc + kt * 16] = p;
        *(short*)(Pb + swzP(w * 16 + 4 * hi + j, (kt * 16 + c) * 2)) = f2b(p);
      }
  }
  // no barrier needed: each wave reads back only the P rows it wrote; Vt was
  // staged before the __syncthreads above.

  // ---- O = P V ----
  f32x4 ov[4];
#pragma unroll
  for (int dt = 0; dt < 4; ++dt) ov[dt] = (f32x4){0.f, 0.f, 0.f, 0.f};
#pragma unroll
  for (int s = 0; s < NS_MAX; ++s)
    if (s < ns) {
      bf16x8 pa = *(const bf16x8*)(Pb + swzP(w * 16 + c, 64 * s + 16 * hi));
#pragma unroll
      for (int dt = 0; dt < 4; ++dt) {
        bf16x8 vb = *(const bf16x8*)(Vb + swzP(dt * 16 + c, 64 * s + 16 * hi));
        ov[dt] = __builtin_amdgcn_mfma_f32_16x16x32_bf16(pa, vb, ov[dt], 0, 0, 0);
      }
    }
#pragma unroll
  for (int dt = 0; dt < 4; ++dt) {
#pragma unroll
    for (int j = 0; j < 4; ++j) {
      optr[(size_t)(q0 + w * 16 + 4 * hi + j) * D_DIM + dt * 16 + c] = ov[dt][j];
    }
  }
}

extern "C" void kernel_launch(void* const* d_in, const int* in_sizes, int n_in,
                              void* d_out, int out_size, void* d_ws, size_t ws_size,
                              hipStream_t stream) {
  const float* q = (const float*)d_in[0];
  const float* k = (const float*)d_in[1];
  const float* v = (const float*)d_in[2];
  float* out = (float*)d_out;
  float* attn = out + (size_t)2 * 16 * T_DIM * D_DIM;  // output first, then attn
  dim3 grid(2 * (T_DIM / QBLK), 2 * 16);               // even x: attention, odd x: zero-fill
  lsa_fused<<<grid, 256, 0, stream>>>(q, k, v, out, attn);
}

// Round 3
// 179.367 us; speedup vs baseline: 1.0702x; 1.0702x over previous
//
#include <hip/hip_runtime.h>
#include <hip/hip_bf16.h>

typedef short bf16x8 __attribute__((ext_vector_type(8)));
typedef float f32x4 __attribute__((ext_vector_type(4)));

#define T_DIM 2048
#define D_DIM 64
#define WIN 128
#define QBLK 64
#define KWMAX 320
#define NKT_MAX 20
#define NS_MAX 10
#define NEGBIG -1e30f

__device__ __forceinline__ short f2b(float x) {
  __hip_bfloat16 h = __float2bfloat16(x);
  return *reinterpret_cast<short*>(&h);
}
__device__ __forceinline__ float b2f(short s) {
  unsigned u = ((unsigned)(unsigned short)s) << 16;
  return __builtin_bit_cast(float, u);
}
__device__ __forceinline__ bf16x8 cvt8(f32x4 a, f32x4 b) {
  bf16x8 r;
  r[0] = f2b(a[0]); r[1] = f2b(a[1]); r[2] = f2b(a[2]); r[3] = f2b(a[3]);
  r[4] = f2b(b[0]); r[5] = f2b(b[1]); r[6] = f2b(b[2]); r[7] = f2b(b[3]);
  return r;
}
// swizzled byte address inside a row-major LDS tile, 640B rows (Vt, P)
__device__ __forceinline__ int swzP(int row, int b) { return row * 640 + (b ^ ((row & 7) << 4)); }

// ---------------- streaming zero-fill of out-of-band attn ----------------
__global__ __launch_bounds__(256) void lsa_fill(float* __restrict__ Ag) {
  const int tid = threadIdx.x;
  const int q0 = blockIdx.x * QBLK;
  const int bh = blockIdx.y;
  int kstart = q0 - WIN; if (kstart < 0) kstart = 0;
  int kend = q0 + QBLK + WIN; if (kend > T_DIM) kend = T_DIM;
  const f32x4 z = {0.f, 0.f, 0.f, 0.f};
  float* arow = Ag + (size_t)bh * ((size_t)T_DIM * T_DIM) + (size_t)q0 * T_DIM;
  for (int r = 0; r < QBLK; ++r, arow += T_DIM) {
    for (int c = tid * 4; c < kstart; c += 1024) *(f32x4*)(arow + c) = z;
    for (int c = kend + tid * 4; c < T_DIM; c += 1024) *(f32x4*)(arow + c) = z;
  }
}

// ---------------- fused banded attention ----------------
__global__ __launch_bounds__(256, 2) void lsa_attn(
    const float* __restrict__ Qg, const float* __restrict__ Kg,
    const float* __restrict__ Vg, float* __restrict__ Og,
    float* __restrict__ Ag) {
  const int tid = threadIdx.x;
  const int q0 = blockIdx.x * QBLK;
  const int bh = blockIdx.y;
  int kstart = q0 - WIN; if (kstart < 0) kstart = 0;
  int kend = q0 + QBLK + WIN; if (kend > T_DIM) kend = T_DIM;
  const int KW = kend - kstart;   // 192 / 256 / 320, always multiple of 32
  const int nkt = KW >> 4;        // 16-wide k tiles
  const int ns = KW >> 5;         // 32-wide k slices
  const int gpr = KW >> 3;        // 8-float groups per band row (24/32/40)

  const float* qptr = Qg + (size_t)bh * (T_DIM * D_DIM);
  const float* kptr = Kg + (size_t)bh * (T_DIM * D_DIM);
  const float* vptr = Vg + (size_t)bh * (T_DIM * D_DIM);
  float* optr = Og + (size_t)bh * (T_DIM * D_DIM);
  float* aptr = Ag + (size_t)bh * ((size_t)T_DIM * T_DIM);

  // LDS: Vt 40KB + P 40KB = 80KB -> 2 blocks/CU
  __shared__ __align__(16) char Vb[D_DIM * 640];
  __shared__ __align__(16) char Pb[QBLK * 640];

  // ---- stage V transposed: Vt[d][k] bf16, 640B rows, swizzled ----
  for (int idx = tid; idx < KW * 16; idx += 256) {
    const int r = idx >> 4, c4 = idx & 15;
    f32x4 f = *(const f32x4*)(vptr + (size_t)(kstart + r) * D_DIM + c4 * 4);
    const int d0 = c4 * 4;
    *(short*)(Vb + swzP(d0 + 0, r * 2)) = f2b(f[0]);
    *(short*)(Vb + swzP(d0 + 1, r * 2)) = f2b(f[1]);
    *(short*)(Vb + swzP(d0 + 2, r * 2)) = f2b(f[2]);
    *(short*)(Vb + swzP(d0 + 3, r * 2)) = f2b(f[3]);
  }
  __syncthreads();

  const int lane = tid & 63;
  const int w = tid >> 6;       // wave id -> q sub-tile (rows w*16 .. w*16+15)
  const int c = lane & 15;      // col within 16x16 tile
  const int hi = lane >> 4;     // 0..3

  // ---- Q A-frags direct from global (fp32 -> bf16) ----
  const float* qrow = qptr + (size_t)(q0 + w * 16 + c) * D_DIM + 8 * hi;
  bf16x8 a0 = cvt8(*(const f32x4*)(qrow),      *(const f32x4*)(qrow + 4));
  bf16x8 a1 = cvt8(*(const f32x4*)(qrow + 32), *(const f32x4*)(qrow + 36));

  // ---- S = Q K^T over the window (K frags direct from global) ----
  f32x4 acc[NKT_MAX];
#pragma unroll
  for (int kt = 0; kt < NKT_MAX; ++kt) {
    acc[kt] = (f32x4){0.f, 0.f, 0.f, 0.f};
    if (kt < nkt) {
      const float* krow = kptr + (size_t)(kstart + kt * 16 + c) * D_DIM + 8 * hi;
      bf16x8 b0 = cvt8(*(const f32x4*)(krow),      *(const f32x4*)(krow + 4));
      bf16x8 b1 = cvt8(*(const f32x4*)(krow + 32), *(const f32x4*)(krow + 36));
      acc[kt] = __builtin_amdgcn_mfma_f32_16x16x32_bf16(a0, b0, acc[kt], 0, 0, 0);
      acc[kt] = __builtin_amdgcn_mfma_f32_16x16x32_bf16(a1, b1, acc[kt], 0, 0, 0);
    }
  }

  // ---- masked softmax (fp32), P -> LDS as bf16 (no global stores here) ----
  const int kgc = kstart + c;
#pragma unroll
  for (int j = 0; j < 4; ++j) {
    const int qrow_i = q0 + w * 16 + 4 * hi + j;
    float m = NEGBIG;
#pragma unroll
    for (int kt = 0; kt < NKT_MAX; ++kt)
      if (kt < nkt) {
        const int kcol = kgc + kt * 16;
        float s = acc[kt][j] * 0.125f;           // 1/sqrt(64)
        int dist = qrow_i - kcol; dist = dist < 0 ? -dist : dist;
        s = (dist <= WIN) ? s : NEGBIG;
        acc[kt][j] = s;
        m = fmaxf(m, s);
      }
    m = fmaxf(m, __shfl_xor(m, 1));
    m = fmaxf(m, __shfl_xor(m, 2));
    m = fmaxf(m, __shfl_xor(m, 4));
    m = fmaxf(m, __shfl_xor(m, 8));
    float sum = 0.f;
#pragma unroll
    for (int kt = 0; kt < NKT_MAX; ++kt)
      if (kt < nkt) {
        float p = __expf(acc[kt][j] - m);
        acc[kt][j] = p;
        sum += p;
      }
    sum += __shfl_xor(sum, 1);
    sum += __shfl_xor(sum, 2);
    sum += __shfl_xor(sum, 4);
    sum += __shfl_xor(sum, 8);
    const float inv = 1.f / sum;
    const int prow = w * 16 + 4 * hi + j;
#pragma unroll
    for (int kt = 0; kt < NKT_MAX; ++kt)
      if (kt < nkt)
        *(short*)(Pb + swzP(prow, (kt * 16 + c) * 2)) = f2b(acc[kt][j] * inv);
  }
  // Each wave only reads back P rows it wrote (rows w*16..w*16+15); Vt was
  // staged before __syncthreads. No extra barrier needed.

  // ---- O = P V ----
  f32x4 ov[4];
#pragma unroll
  for (int dt = 0; dt < 4; ++dt) ov[dt] = (f32x4){0.f, 0.f, 0.f, 0.f};
#pragma unroll
  for (int s = 0; s < NS_MAX; ++s)
    if (s < ns) {
      bf16x8 pa = *(const bf16x8*)(Pb + swzP(w * 16 + c, 64 * s + 16 * hi));
#pragma unroll
      for (int dt = 0; dt < 4; ++dt) {
        bf16x8 vb = *(const bf16x8*)(Vb + swzP(dt * 16 + c, 64 * s + 16 * hi));
        ov[dt] = __builtin_amdgcn_mfma_f32_16x16x32_bf16(pa, vb, ov[dt], 0, 0, 0);
      }
    }

  // ---- band write-back: wide coalesced stores from Pb (bf16 -> fp32) ----
  for (int rr = 0; rr < 16; ++rr) {
    const int r = w * 16 + rr;
    if (lane < gpr) {
      bf16x8 pv = *(const bf16x8*)(Pb + swzP(r, lane * 16));
      f32x4 lo, hixv;
      lo[0] = b2f(pv[0]); lo[1] = b2f(pv[1]); lo[2] = b2f(pv[2]); lo[3] = b2f(pv[3]);
      hixv[0] = b2f(pv[4]); hixv[1] = b2f(pv[5]); hixv[2] = b2f(pv[6]); hixv[3] = b2f(pv[7]);
      float* dst = aptr + (size_t)(q0 + r) * T_DIM + kstart + lane * 8;
      *(f32x4*)dst = lo;
      *(f32x4*)(dst + 4) = hixv;
    }
  }

  // ---- O store ----
#pragma unroll
  for (int dt = 0; dt < 4; ++dt) {
#pragma unroll
    for (int j = 0; j < 4; ++j) {
      optr[(size_t)(q0 + w * 16 + 4 * hi + j) * D_DIM + dt * 16 + c] = ov[dt][j];
    }
  }
}

extern "C" void kernel_launch(void* const* d_in, const int* in_sizes, int n_in,
                              void* d_out, int out_size, void* d_ws, size_t ws_size,
                              hipStream_t stream) {
  const float* q = (const float*)d_in[0];
  const float* k = (const float*)d_in[1];
  const float* v = (const float*)d_in[2];
  float* out = (float*)d_out;
  float* attn = out + (size_t)2 * 16 * T_DIM * D_DIM;  // output first, then attn
  dim3 grid(T_DIM / QBLK, 2 * 16);
  lsa_fill<<<grid, 256, 0, stream>>>(attn);
  lsa_attn<<<grid, 256, 0, stream>>>(q, k, v, out, attn);
}

// Round 4
// 156.816 us; speedup vs baseline: 1.2241x; 1.1438x over previous
//
#include <hip/hip_runtime.h>
#include <hip/hip_bf16.h>

typedef short bf16x8 __attribute__((ext_vector_type(8)));
typedef float f32x4 __attribute__((ext_vector_type(4)));

#define T_DIM 2048
#define D_DIM 64
#define WIN 128
#define QBLK 64
#define NEGBIG -1e30f
#define NZE 116   // max 16B zero stores per thread: rows 64 x cols<=1856 /256thr /16B

__device__ __forceinline__ short f2b(float x) {
  __hip_bfloat16 h = __float2bfloat16(x);
  return *reinterpret_cast<short*>(&h);
}
__device__ __forceinline__ float b2f(short s) {
  unsigned u = ((unsigned)(unsigned short)s) << 16;
  return __builtin_bit_cast(float, u);
}
__device__ __forceinline__ bf16x8 cvt8(f32x4 a, f32x4 b) {
  bf16x8 r;
  r[0] = f2b(a[0]); r[1] = f2b(a[1]); r[2] = f2b(a[2]); r[3] = f2b(a[3]);
  r[4] = f2b(b[0]); r[5] = f2b(b[1]); r[6] = f2b(b[2]); r[7] = f2b(b[3]);
  return r;
}
// swizzled byte address inside Vt tile, 640B rows
__device__ __forceinline__ int swzV(int row, int b) { return row * 640 + (b ^ ((row & 7) << 4)); }

// emit up to n 16B zero-stores of this block's out-of-window attn region.
// mapping: emission e -> row (tid>>3)+32*(e&1), col-group (tid&7)+8*(e>>1)
// => 8 lanes write 128B contiguous per row. Guard zc<rowg skips done work.
#define ZEMIT(n) do { \
  for (int _i = 0; _i < (n); ++_i) { \
    if (zt < NZE) { \
      const int zr = (tid >> 3) + 32 * (zt & 1); \
      const int zc = (tid & 7) + 8 * (zt >> 1); \
      if (zc < rowg) { \
        const int c4 = zc << 2; \
        const int col = (c4 < Lw) ? c4 : (kend + c4 - Lw); \
        __builtin_nontemporal_store(zvec, (f32x4*)(azero + (size_t)zr * T_DIM + col)); \
      } \
      ++zt; \
    } \
  } } while (0)

__global__ __launch_bounds__(256, 3) void lsa_one(
    const float* __restrict__ Qg, const float* __restrict__ Kg,
    const float* __restrict__ Vg, float* __restrict__ Og,
    float* __restrict__ Ag) {
  const int tid = threadIdx.x;
  // XCD-chunked swizzle: XCD x hosts work ids [128x,128x+128) = 4 bh, 32 q-blocks each
  const int work = ((blockIdx.x & 7) << 7) + (blockIdx.x >> 3);
  const int bh = work >> 5;
  const int qb = work & 31;
  const int q0 = qb * QBLK;
  int kstart = q0 - WIN; if (kstart < 0) kstart = 0;
  int kend = q0 + QBLK + WIN; if (kend > T_DIM) kend = T_DIM;
  const int KW = kend - kstart;   // 192/256/320, multiple of 32
  const int nkt = KW >> 4;
  const int ns = KW >> 5;
  const int Lw = kstart;
  const int rowg = (Lw + (T_DIM - kend)) >> 2;   // f32x4 groups of zeros per row

  const float* qptr = Qg + (size_t)bh * (T_DIM * D_DIM);
  const float* kptr = Kg + (size_t)bh * (T_DIM * D_DIM);
  const float* vptr = Vg + (size_t)bh * (T_DIM * D_DIM);
  float* optr = Og + (size_t)bh * (T_DIM * D_DIM);
  float* aptr = Ag + (size_t)bh * ((size_t)T_DIM * T_DIM);
  float* azero = aptr + (size_t)q0 * T_DIM;

  // LDS: Vt 40KB + P staging 4KB = 44KB -> 3 blocks/CU
  __shared__ __align__(16) char Vb[D_DIM * 640];
  __shared__ __align__(16) char Pb[4 * 1024];   // per-wave 16x32 bf16, 64B rows, xor-swz

  // ---- stage V transposed: Vt[d][k] bf16 ----
  for (int idx = tid; idx < KW * 16; idx += 256) {
    const int r = idx >> 4, c4 = idx & 15;
    f32x4 f = *(const f32x4*)(vptr + (size_t)(kstart + r) * D_DIM + c4 * 4);
    const int d0 = c4 * 4;
    *(short*)(Vb + swzV(d0 + 0, r * 2)) = f2b(f[0]);
    *(short*)(Vb + swzV(d0 + 1, r * 2)) = f2b(f[1]);
    *(short*)(Vb + swzV(d0 + 2, r * 2)) = f2b(f[2]);
    *(short*)(Vb + swzV(d0 + 3, r * 2)) = f2b(f[3]);
  }
  __syncthreads();

  const int lane = tid & 63, w = tid >> 6, c = lane & 15, hi = lane >> 4;
  const f32x4 zvec = {0.f, 0.f, 0.f, 0.f};
  int zt = 0;

  // Q A-frags (rows of this wave's 16-q tile)
  const float* qrow = qptr + (size_t)(q0 + w * 16 + c) * D_DIM + 8 * hi;
  const bf16x8 a0 = cvt8(*(const f32x4*)qrow, *(const f32x4*)(qrow + 4));
  const bf16x8 a1 = cvt8(*(const f32x4*)(qrow + 32), *(const f32x4*)(qrow + 36));

  // per-wave live k-tile range (mask makes any extra tile a no-op)
  int klo = q0 + w * 16 - WIN - kstart; if (klo < 0) klo = 0;
  const int kt0 = klo >> 4;
  int kt1 = (q0 + w * 16 + 15 + WIN + 1 - kstart + 15) >> 4; if (kt1 > nkt) kt1 = nkt;

  // ---- pass A: online (m,l) per row, one k-tile live at a time ----
  float m[4] = {NEGBIG, NEGBIG, NEGBIG, NEGBIG};
  float l[4] = {0.f, 0.f, 0.f, 0.f};
  for (int kt = kt0; kt < kt1; ++kt) {
    const float* krow = kptr + (size_t)(kstart + kt * 16 + c) * D_DIM + 8 * hi;
    const bf16x8 b0 = cvt8(*(const f32x4*)krow, *(const f32x4*)(krow + 4));
    const bf16x8 b1 = cvt8(*(const f32x4*)(krow + 32), *(const f32x4*)(krow + 36));
    f32x4 acc = {0.f, 0.f, 0.f, 0.f};
    acc = __builtin_amdgcn_mfma_f32_16x16x32_bf16(a0, b0, acc, 0, 0, 0);
    acc = __builtin_amdgcn_mfma_f32_16x16x32_bf16(a1, b1, acc, 0, 0, 0);
    const int kcol = kstart + kt * 16 + c;
#pragma unroll
    for (int j = 0; j < 4; ++j) {
      const int qr = q0 + w * 16 + 4 * hi + j;
      float s = acc[j] * 0.125f;
      int dist = qr - kcol; dist = dist < 0 ? -dist : dist;
      s = (dist <= WIN) ? s : NEGBIG;   // tile kt0 is fully live per row -> m real before any mask
      const float mn = fmaxf(m[j], s);
      l[j] = l[j] * __expf(m[j] - mn) + __expf(s - mn);
      m[j] = mn;
    }
    ZEMIT(4);
  }
  // cross-lane (c-group) combine of (m,l)
#pragma unroll
  for (int j = 0; j < 4; ++j) {
#pragma unroll
    for (int d = 1; d <= 8; d <<= 1) {
      const float mo = __shfl_xor(m[j], d);
      const float lo = __shfl_xor(l[j], d);
      const float mn = fmaxf(m[j], mo);
      l[j] = l[j] * __expf(m[j] - mn) + lo * __expf(mo - mn);
      m[j] = mn;
    }
  }
  float il[4];
#pragma unroll
  for (int j = 0; j < 4; ++j) il[j] = 1.0f / l[j];

  // ---- pass B: recompute S slice-by-slice, emit P (band + LDS) + PV ----
  char* pw = Pb + w * 1024;
  float* arow = aptr + (size_t)(q0 + w * 16 + c) * T_DIM + kstart;  // this lane's band row
  const int s0 = kt0 >> 1, s1 = (kt1 + 1) >> 1;

  f32x4 ov[4];
#pragma unroll
  for (int dt = 0; dt < 4; ++dt) ov[dt] = zvec;

  for (int s = 0; s < ns; ++s) {
    float* dst = arow + 32 * s + 8 * hi;
    if (s < s0 || s >= s1) {   // wave-uniform dead slice: all-masked -> zeros
      __builtin_nontemporal_store(zvec, (f32x4*)dst);
      __builtin_nontemporal_store(zvec, (f32x4*)(dst + 4));
      ZEMIT(5);
      continue;
    }
#pragma unroll
    for (int h = 0; h < 2; ++h) {
      const int kt = 2 * s + h;
      const float* krow = kptr + (size_t)(kstart + kt * 16 + c) * D_DIM + 8 * hi;
      const bf16x8 b0 = cvt8(*(const f32x4*)krow, *(const f32x4*)(krow + 4));
      const bf16x8 b1 = cvt8(*(const f32x4*)(krow + 32), *(const f32x4*)(krow + 36));
      f32x4 acc = {0.f, 0.f, 0.f, 0.f};
      acc = __builtin_amdgcn_mfma_f32_16x16x32_bf16(a0, b0, acc, 0, 0, 0);
      acc = __builtin_amdgcn_mfma_f32_16x16x32_bf16(a1, b1, acc, 0, 0, 0);
      const int kcol = kstart + kt * 16 + c;
#pragma unroll
      for (int j = 0; j < 4; ++j) {
        const int qr = q0 + w * 16 + 4 * hi + j;
        int dist = qr - kcol; dist = dist < 0 ? -dist : dist;
        const float p = (dist <= WIN) ? __expf(acc[j] * 0.125f - m[j]) * il[j] : 0.f;
        // P staging: row=4hi+j (64B rows), natural byte 2c+32h, xor (row&3)<<4
        *(short*)(pw + (4 * hi + j) * 64 + ((2 * c + 32 * h) ^ (j << 4))) = f2b(p);
      }
    }
    // A-frag: row c, natural bytes 16hi..16hi+15 (same-wave DS ops are in-order)
    const bf16x8 pa = *(const bf16x8*)(pw + c * 64 + ((16 * hi) ^ ((c & 3) << 4)));
    f32x4 o1, o2;
    o1[0] = b2f(pa[0]); o1[1] = b2f(pa[1]); o1[2] = b2f(pa[2]); o1[3] = b2f(pa[3]);
    o2[0] = b2f(pa[4]); o2[1] = b2f(pa[5]); o2[2] = b2f(pa[6]); o2[3] = b2f(pa[7]);
    __builtin_nontemporal_store(o1, (f32x4*)dst);
    __builtin_nontemporal_store(o2, (f32x4*)(dst + 4));
#pragma unroll
    for (int dt = 0; dt < 4; ++dt) {
      const bf16x8 vb = *(const bf16x8*)(Vb + swzV(dt * 16 + c, 64 * s + 16 * hi));
      ov[dt] = __builtin_amdgcn_mfma_f32_16x16x32_bf16(pa, vb, ov[dt], 0, 0, 0);
    }
    ZEMIT(5);
  }
  while (zt < NZE) ZEMIT(1);

  // ---- O store ----
#pragma unroll
  for (int dt = 0; dt < 4; ++dt)
#pragma unroll
    for (int j = 0; j < 4; ++j)
      __builtin_nontemporal_store(
          ov[dt][j], optr + (size_t)(q0 + w * 16 + 4 * hi + j) * D_DIM + dt * 16 + c);
}

extern "C" void kernel_launch(void* const* d_in, const int* in_sizes, int n_in,
                              void* d_out, int out_size, void* d_ws, size_t ws_size,
                              hipStream_t stream) {
  const float* q = (const float*)d_in[0];
  const float* k = (const float*)d_in[1];
  const float* v = (const float*)d_in[2];
  float* out = (float*)d_out;
  float* attn = out + (size_t)2 * 16 * T_DIM * D_DIM;  // output first, then attn
  lsa_one<<<dim3(2 * 16 * (T_DIM / QBLK)), dim3(256), 0, stream>>>(q, k, v, out, attn);
}